// Round 8
// baseline (470.834 us; speedup 1.0000x reference)
//
#include <hip/hip_runtime.h>
#include <hip/hip_fp16.h>

#define WAVE 64
#define NXCD 8
#define NRMAX 200
#define RSTRIDE 17      // float4 units: 272B row stride -> per-rel start-bank offset 4*(rel%8)
#define HOP_TPB 1024
#define HOP_BLOCKS 512
#define CSR_BLOCKS 2048
#define CSR_TPB 256
#define CAP 16          // slots per entity; P(Poisson(5)>16)~1.4e-5 -> ~3 ovf triples/run
#define OVF_CAP 32768
#define NSTRIPE 64
#define REG_CAP 2304    // per (bin,stripe) region capacity; mean 1953, +8.5 sigma

// rT layout: [layer][N_R][64]  (batch innermost, matches lane)
__global__ void compute_r_kernel(const float* __restrict__ q,
                                 const float* __restrict__ W1, const float* __restrict__ b1,
                                 const float* __restrict__ W2, const float* __restrict__ b2,
                                 const float* __restrict__ W3, const float* __restrict__ b3,
                                 float* __restrict__ rT, int N_R, int N_W2V) {
    int lane = threadIdx.x & 63;
    int wv   = threadIdx.x >> 6;
    int b    = blockIdx.y * 4 + wv;
    int it   = blockIdx.x * 64 + lane;
    if (it >= 3 * N_R) return;
    int l = it / N_R;
    int j = it - l * N_R;
    const float* W  = (l == 0) ? W1 : (l == 1) ? W2 : W3;
    const float* bv = (l == 0) ? b1 : (l == 1) ? b2 : b3;
    const float* qrow = q + (size_t)b * N_W2V;
    float a0 = 0.f, a1 = 0.f, a2 = 0.f, a3 = 0.f;
    int k = 0;
    for (; k + 4 <= N_W2V; k += 4) {
        a0 = fmaf(qrow[k + 0], W[(size_t)(k + 0) * N_R + j], a0);
        a1 = fmaf(qrow[k + 1], W[(size_t)(k + 1) * N_R + j], a1);
        a2 = fmaf(qrow[k + 2], W[(size_t)(k + 2) * N_R + j], a2);
        a3 = fmaf(qrow[k + 3], W[(size_t)(k + 3) * N_R + j], a3);
    }
    for (; k < N_W2V; ++k)
        a0 = fmaf(qrow[k], W[(size_t)k * N_R + j], a0);
    rT[(size_t)it * WAVE + b] = bv[j] + ((a0 + a1) + (a2 + a3));
}

// x (B=64, N_E) fp32 -> xT (N_E, 64) fp16. tile is written [batch][entity];
// fp16 store must read tile[2j][ei] (R3 bug was the swap).
__global__ void transpose_in_f16_kernel(const float* __restrict__ in, __half2* __restrict__ out, int N_E) {
    __shared__ float tile[64][65];
    int e0 = blockIdx.x * 64;
    int li = threadIdx.x & 63;
    int lo = threadIdx.x >> 6;
    #pragma unroll
    for (int k = 0; k < 16; ++k) {
        int b = lo + 4 * k;
        int e = e0 + li;
        tile[b][li] = (e < N_E) ? in[(size_t)b * N_E + e] : 0.0f;
    }
    __syncthreads();
    #pragma unroll
    for (int k = 0; k < 8; ++k) {
        int idx = k * 256 + threadIdx.x;     // 0..2047
        int ei  = idx >> 5;                  // entity 0..63
        int j   = idx & 31;                  // half2 col (batch pair) 0..31
        int e   = e0 + ei;
        if (e < N_E)
            out[(size_t)e * 32 + j] = __floats2half2_rn(tile[2 * j][ei], tile[2 * j + 1][ei]);
    }
}

// ---- bucket build ----
// R5: XCD group only touches its own entity slice (write coherence).
// R14: one fixed-capacity atomic pass; overflow list merged post-hop.
// R15 lesson: nt loads cut WRITE 65->52MB but broke L3 stream sharing
// (FETCH 49->72MB) -> net regression. Root cause is structural: 12MB
// stream/XCD thrashes the 4MB L2 holding slots+cnt (1.7MB), so bucket
// lines evict between their ~5 touches (5x write amplification).
// R16: two-pass bin partition. Pass1 bins triples by obj range into
// 8 bins x 64 stripes (wave-ballot compaction, leader-atomic cursors,
// wave-contiguous writes). Pass2: XCD group streams ONLY its bin
// (~1MB -- fits L2 with slots+cnt) -> bucket writes coalesce in L2.

__global__ void partition_kernel(const int* __restrict__ subj, const int* __restrict__ rel,
                                 const int* __restrict__ obj,
                                 int* __restrict__ bcur, uint2* __restrict__ regions,
                                 int* __restrict__ novf, int* __restrict__ ovf_obj,
                                 unsigned* __restrict__ ovf_pk, int nT, int nE) {
    int sh = (nE + NXCD - 1) / NXCD;
    int lane = threadIdx.x & 63;
    int stripe = blockIdx.x & (NSTRIPE - 1);
    int tid = blockIdx.x * blockDim.x + threadIdx.x;
    int nw  = (gridDim.x * blockDim.x) >> 6;     // total waves
    int wid = tid >> 6;
    for (long tb = (long)wid * 64; tb < nT; tb += (long)nw * 64) {   // wave-uniform loop
        int t = (int)tb + lane;
        bool v = t < nT;
        int oo = v ? obj[t] : 0;
        unsigned pk = v ? ((unsigned)subj[t] | ((unsigned)rel[t] << 18)) : 0u;
        int b = v ? (oo / sh) : 8;               // 0..7 for valid lanes
        #pragma unroll
        for (int bin = 0; bin < 8; ++bin) {
            unsigned long long m = __ballot(b == bin);
            if (!m) continue;                    // wave-uniform
            int cnt_ = __popcll(m);
            int leader = __ffsll((long long)m) - 1;
            int base = 0;
            if (lane == leader) base = atomicAdd(&bcur[bin * NSTRIPE + stripe], cnt_);
            base = __shfl(base, leader);
            if (b == bin) {
                int off = base + __popcll(m & ((1ull << lane) - 1ull));
                if (off < REG_CAP)
                    regions[(size_t)(bin * NSTRIPE + stripe) * REG_CAP + off] = make_uint2((unsigned)oo, pk);
                else {
                    int oi = atomicAdd(novf, 1);
                    if (oi < OVF_CAP) { ovf_obj[oi] = oo; ovf_pk[oi] = pk; }
                }
            }
        }
    }
}

// Pass2: group g = blockIdx&7 (one XCD) drains bin g. 256 blocks/group;
// 4 blocks per stripe (q>>6), 1024 threads cover ~1953 entries in 2 iters.
__global__ void scatter_bins_kernel(const int* __restrict__ bcur, const uint2* __restrict__ regions,
                                    int* __restrict__ cnt, unsigned* __restrict__ slots,
                                    int* __restrict__ novf, int* __restrict__ ovf_obj,
                                    unsigned* __restrict__ ovf_pk) {
    int g = blockIdx.x & (NXCD - 1);
    int q = blockIdx.x >> 3;                     // 0..255 within group
    int s = q & (NSTRIPE - 1);                   // stripe
    int sub = q >> 6;                            // 0..3
    int n = min(bcur[g * NSTRIPE + s], REG_CAP);
    const uint2* reg = regions + (size_t)(g * NSTRIPE + s) * REG_CAP;
    for (int i = sub * blockDim.x + threadIdx.x; i < n; i += 4 * blockDim.x) {
        uint2 e = reg[i];
        int oo = (int)e.x;
        int slot = atomicAdd(&cnt[oo], 1);
        if (slot < CAP) slots[(size_t)oo * CAP + slot] = e.y;
        else {
            int oi = atomicAdd(novf, 1);
            if (oi < OVF_CAP) { ovf_obj[oi] = oo; ovf_pk[oi] = e.y; }
        }
    }
}

// ---- hops ----
// R10: fp16 intermediates. R12: fp16 x0 + unroll-8 issue-early gathers.
// R13: gather FETCH matches the distinct-line floor -> hops treated as
// random-access-BW bound (~3.5TB/s); unchanged as control.
// R14: bucket = slots[e*CAP ..), one 64B line; no tail loop.

__device__ __forceinline__ float4 h4_to_f4(uint2 v) {
    float2 f0 = __half22float2(*(__half2*)&v.x);
    float2 f1 = __half22float2(*(__half2*)&v.y);
    return make_float4(f0.x, f0.y, f1.x, f1.y);
}

__device__ __forceinline__ uint2 pack_half4(float4 a) {
    __half2 h0 = __floats2half2_rn(a.x, a.y);
    __half2 h1 = __floats2half2_rn(a.z, a.w);
    uint2 v;
    v.x = *(unsigned*)&h0;
    v.y = *(unsigned*)&h1;
    return v;
}

// 4 entities/wave, 16 lanes x uint2 (8B) per fp16 entity row.
__device__ __forceinline__ float4 hop_accum4(const uint2* __restrict__ xp,
                                             const float4* __restrict__ r_lds,
                                             const int* __restrict__ cnt,
                                             const unsigned* __restrict__ slots,
                                             int e, int g, int c, int nE) {
    float4 acc = make_float4(0.f, 0.f, 0.f, 0.f);
    int len = (e < nE) ? min(cnt[e], CAP) : 0;
    unsigned pv = (c < len) ? slots[(size_t)e * CAP + c] : 0u;  // whole bucket = one 64B line
    int m = max(len, __shfl_xor(len, 16));            // wave-max over the 4 groups
    m = max(m, __shfl_xor(m, 32));
    for (int j0 = 0; j0 < m; j0 += 8) {
        uint2 xv[8];
        unsigned pr[8];
        #pragma unroll
        for (int u = 0; u < 8; ++u) {                 // issue all 8 gathers first
            int jj = max(min(j0 + u, len - 1), 0);    // clamp: dup loads hit hot lines
            unsigned p = __shfl(pv, (g << 4) + jj);   // per-lane src index: group-local broadcast
            pr[u] = p >> 18;
            xv[u] = xp[(size_t)(p & 0x3FFFFu) * 16 + c];
        }
        #pragma unroll
        for (int u = 0; u < 8; ++u) {                 // consume with LDS-r FMAs
            if (j0 + u < len) {
                float4 rv = r_lds[pr[u] * RSTRIDE + c];
                float4 xf = h4_to_f4(xv[u]);
                acc.x = fmaf(xf.x, rv.x, acc.x);
                acc.y = fmaf(xf.y, rv.y, acc.y);
                acc.z = fmaf(xf.z, rv.z, acc.z);
                acc.w = fmaf(xf.w, rv.w, acc.w);
            }
        }
    }
    return acc;
}

// hops 1-2: 1024-thread blocks (16 waves x 4 entities = 64-entity tiles),
// grid-stride, 512 resident blocks (2/CU, 32 waves/CU). fp16 in, fp16 out.
__global__ __launch_bounds__(HOP_TPB, 8)
void hop_mid_kernel(const uint2* __restrict__ xp, const float4* __restrict__ rT4,
                    const int* __restrict__ cnt, const unsigned* __restrict__ slots,
                    uint2* __restrict__ yh, int nE, int nR) {
    __shared__ float4 r_lds[NRMAX * RSTRIDE];
    for (int i = threadIdx.x; i < nR * 16; i += HOP_TPB)
        r_lds[(i >> 4) * RSTRIDE + (i & 15)] = rT4[i];
    __syncthreads();
    int lane = threadIdx.x & 63;
    int g = lane >> 4, c = lane & 15;
    int wv = threadIdx.x >> 6;                   // 0..15
    int nTiles = (nE + 63) >> 6;
    for (int t = blockIdx.x; t < nTiles; t += gridDim.x) {
        int e = t * 64 + wv * 4 + g;
        float4 acc = hop_accum4(xp, r_lds, cnt, slots, e, g, c, nE);
        if (e < nE) yh[(size_t)e * 16 + c] = pack_half4(acc);
    }
}

// hop 3 fused with output transpose: 64-entity LDS tile, stores (B, N_E) fp32.
__global__ __launch_bounds__(HOP_TPB, 8)
void hop_out_kernel(const uint2* __restrict__ xp, const float4* __restrict__ rT4,
                    const int* __restrict__ cnt, const unsigned* __restrict__ slots,
                    float* __restrict__ out, int nE, int nR) {
    __shared__ float4 r_lds[NRMAX * RSTRIDE];
    __shared__ float tile[64][65];
    for (int i = threadIdx.x; i < nR * 16; i += HOP_TPB)
        r_lds[(i >> 4) * RSTRIDE + (i & 15)] = rT4[i];
    __syncthreads();
    int lane = threadIdx.x & 63;
    int g = lane >> 4, c = lane & 15;
    int wv = threadIdx.x >> 6;                   // 0..15
    int nTiles = (nE + 63) >> 6;
    for (int t = blockIdx.x; t < nTiles; t += gridDim.x) {
        int e0 = t * 64;
        int ei = wv * 4 + g;                     // 0..63 unique per (wv,g)
        float4 acc = hop_accum4(xp, r_lds, cnt, slots, e0 + ei, g, c, nE);
        tile[ei][4 * c + 0] = acc.x;
        tile[ei][4 * c + 1] = acc.y;
        tile[ei][4 * c + 2] = acc.z;
        tile[ei][4 * c + 3] = acc.w;
        __syncthreads();
        #pragma unroll
        for (int k = 0; k < 4; ++k) {
            int b = wv * 4 + k;
            int e = e0 + lane;
            if (e < nE) out[(size_t)b * nE + e] = tile[lane][b];
        }
        __syncthreads();                         // tile reused next iteration
    }
}

// ---- overflow merge (exercised every run on ~3 triples) ----
__device__ __forceinline__ void atom_add_h2(unsigned* addr, float a, float b) {
    unsigned old = __atomic_load_n(addr, __ATOMIC_RELAXED), assumed;
    do {
        assumed = old;
        float2 f = __half22float2(*(__half2*)&assumed);
        __half2 nh = __floats2half2_rn(f.x + a, f.y + b);
        old = atomicCAS(addr, assumed, *(unsigned*)&nh);
    } while (old != assumed);
}

// adds overflow contributions into fp16 (N_E,64) intermediate
__global__ void ovf_mid_kernel(const uint2* __restrict__ xp, const float* __restrict__ rTl,
                               const int* __restrict__ novf, const int* __restrict__ ovf_obj,
                               const unsigned* __restrict__ ovf_pk, uint2* __restrict__ yh) {
    int n = min(*novf, OVF_CAP);
    int c = threadIdx.x & 15, grp = threadIdx.x >> 4;   // 64 threads = 4 groups
    for (int i = blockIdx.x * 4 + grp; i < n; i += gridDim.x * 4) {
        int o = ovf_obj[i];
        unsigned p = ovf_pk[i];
        float4 xf = h4_to_f4(xp[(size_t)(p & 0x3FFFFu) * 16 + c]);
        const float* rr = rTl + (size_t)(p >> 18) * 64 + c * 4;
        unsigned* w = (unsigned*)&yh[(size_t)o * 16 + c];
        atom_add_h2(w,     xf.x * rr[0], xf.y * rr[1]);
        atom_add_h2(w + 1, xf.z * rr[2], xf.w * rr[3]);
    }
}

// adds overflow contributions into fp32 (B, N_E) output
__global__ void ovf_out_kernel(const uint2* __restrict__ xp, const float* __restrict__ rTl,
                               const int* __restrict__ novf, const int* __restrict__ ovf_obj,
                               const unsigned* __restrict__ ovf_pk, float* __restrict__ out, int nE) {
    int n = min(*novf, OVF_CAP);
    int c = threadIdx.x & 15, grp = threadIdx.x >> 4;
    for (int i = blockIdx.x * 4 + grp; i < n; i += gridDim.x * 4) {
        int o = ovf_obj[i];
        unsigned p = ovf_pk[i];
        float4 xf = h4_to_f4(xp[(size_t)(p & 0x3FFFFu) * 16 + c]);
        const float* rr = rTl + (size_t)(p >> 18) * 64 + c * 4;
        atomicAdd(&out[(size_t)(4 * c + 0) * nE + o], xf.x * rr[0]);
        atomicAdd(&out[(size_t)(4 * c + 1) * nE + o], xf.y * rr[1]);
        atomicAdd(&out[(size_t)(4 * c + 2) * nE + o], xf.z * rr[2]);
        atomicAdd(&out[(size_t)(4 * c + 3) * nE + o], xf.w * rr[3]);
    }
}

extern "C" void kernel_launch(void* const* d_in, const int* in_sizes, int n_in,
                              void* d_out, int out_size, void* d_ws, size_t ws_size,
                              hipStream_t stream) {
    const float* x  = (const float*)d_in[0];
    const float* q  = (const float*)d_in[1];
    const float* W1 = (const float*)d_in[2];
    const float* b1 = (const float*)d_in[3];
    const float* W2 = (const float*)d_in[4];
    const float* b2 = (const float*)d_in[5];
    const float* W3 = (const float*)d_in[6];
    const float* b3 = (const float*)d_in[7];
    const int* subj = (const int*)d_in[8];
    const int* rel  = (const int*)d_in[9];
    const int* obj  = (const int*)d_in[10];
    // n_hop (d_in[11]) is the constant 3 per the reference; hops hardcoded.

    const int B     = 64;
    const int N_E   = in_sizes[0] / B;   // 200000
    const int N_W2V = in_sizes[1] / B;   // 300
    const int N_R   = in_sizes[3];       // 200
    const int N_T   = in_sizes[8];       // 1000000

    const size_t h16bytes = (size_t)N_E * B * sizeof(__half);   // 25.6MB per fp16 buffer

    // ws layout: [cnt nE][novf 4][bcur 512][ovf_obj][ovf_pk][slots nE*CAP]
    //            [regions 512*REG_CAP uint2][rT][X0 fp16][H1 fp16?]
    int*      cnt     = (int*)d_ws;
    int*      novf    = cnt + N_E;
    int*      bcur    = novf + 4;
    int*      ovf_obj = bcur + NXCD * NSTRIPE;
    unsigned* ovf_pk  = (unsigned*)(ovf_obj + OVF_CAP);
    unsigned* slots   = ovf_pk + OVF_CAP;
    uint2*    regions = (uint2*)(slots + (size_t)N_E * CAP);
    char*     rT_raw  = (char*)(regions + (size_t)NXCD * NSTRIPE * REG_CAP);
    float*    rT      = (float*)(((uintptr_t)rT_raw + 15) & ~(uintptr_t)15);
    char*     X0      = (char*)(rT + (size_t)3 * N_R * B);      // 16B-aligned
    size_t used = (size_t)(X0 - (char*)d_ws) + h16bytes;

    char* H1;
    if (ws_size >= used + h16bytes) {
        H1 = X0 + h16bytes;
        used += h16bytes;
    } else {
        H1 = (char*)d_out;   // 25.6MB scratch in the 51.2MB output; dead before hop3's write
    }
    char* H2 = X0;           // X0 dead after hop1

    // 1) r for all three layers
    {
        dim3 rgrid((3 * N_R + 63) / 64, B / 4);
        compute_r_kernel<<<rgrid, 256, 0, stream>>>(q, W1, b1, W2, b2, W3, b3, rT, N_R, N_W2V);
    }

    // 2) transpose x -> X0 (fp16)
    int tgrid = (N_E + 63) / 64;
    transpose_in_f16_kernel<<<tgrid, 256, 0, stream>>>(x, (__half2*)X0, N_E);

    // 3) bucket build: partition by obj range, then L2-resident per-XCD scatter
    hipMemsetAsync(cnt, 0, (size_t)(N_E + 4 + NXCD * NSTRIPE) * sizeof(int), stream);
    partition_kernel<<<CSR_BLOCKS, CSR_TPB, 0, stream>>>(
        subj, rel, obj, bcur, regions, novf, ovf_obj, ovf_pk, N_T, N_E);
    scatter_bins_kernel<<<CSR_BLOCKS, CSR_TPB, 0, stream>>>(
        bcur, regions, cnt, slots, novf, ovf_obj, ovf_pk);

    // 4) three hops (+ tiny overflow merge after each); hop3 fuses the transpose
    int nTiles  = (N_E + 63) / 64;                 // 3125
    int hblocks = nTiles < HOP_BLOCKS ? nTiles : HOP_BLOCKS;
    const float* rT1 = rT;
    const float* rT2 = rT + (size_t)1 * N_R * B;
    const float* rT3 = rT + (size_t)2 * N_R * B;

    hop_mid_kernel<<<hblocks, HOP_TPB, 0, stream>>>(
        (const uint2*)X0, (const float4*)rT1, cnt, slots, (uint2*)H1, N_E, N_R);
    ovf_mid_kernel<<<16, 64, 0, stream>>>(
        (const uint2*)X0, rT1, novf, ovf_obj, ovf_pk, (uint2*)H1);

    hop_mid_kernel<<<hblocks, HOP_TPB, 0, stream>>>(
        (const uint2*)H1, (const float4*)rT2, cnt, slots, (uint2*)H2, N_E, N_R);
    ovf_mid_kernel<<<16, 64, 0, stream>>>(
        (const uint2*)H1, rT2, novf, ovf_obj, ovf_pk, (uint2*)H2);

    hop_out_kernel<<<hblocks, HOP_TPB, 0, stream>>>(
        (const uint2*)H2, (const float4*)rT3, cnt, slots, (float*)d_out, N_E, N_R);
    ovf_out_kernel<<<16, 64, 0, stream>>>(
        (const uint2*)H2, rT3, novf, ovf_obj, ovf_pk, (float*)d_out, N_E);
}

// Round 9
// 345.086 us; speedup vs baseline: 1.3644x; 1.3644x over previous
//
#include <hip/hip_runtime.h>
#include <hip/hip_fp16.h>

#define WAVE 64
#define NXCD 8
#define NRMAX 200
#define RSTRIDE 17      // float4 units: 272B row stride -> per-rel start-bank offset 4*(rel%8)
#define HOP_TPB 1024
#define HOP_BLOCKS 512
#define CSR_BLOCKS 2048
#define CSR_TPB 256
#define CAP 16          // slots per entity; P(Poisson(5)>16)~1.4e-5 -> ~3 ovf triples/run
#define OVF_CAP 32768

typedef int v4i __attribute__((ext_vector_type(4)));

// ---- fused prologue: transpose (blocks [0,tgrid)) + compute_r (next 160)
//      + cnt zeroing (rest). Replaces 3 dispatches + memset with 1 (R17). ----

__global__ void prologue_kernel(const float* __restrict__ x, const float* __restrict__ q,
                                const float* __restrict__ W1, const float* __restrict__ b1,
                                const float* __restrict__ W2, const float* __restrict__ b2,
                                const float* __restrict__ W3, const float* __restrict__ b3,
                                float* __restrict__ rT, __half2* __restrict__ xT,
                                int* __restrict__ cnt, int N_E, int N_R, int N_W2V,
                                int tgrid, int nrx, int rblocks, int zcount) {
    __shared__ float tile[64][65];
    int bid = blockIdx.x;
    if (bid < tgrid) {
        // x (B=64, N_E) fp32 -> xT (N_E, 64) fp16. tile written [batch][entity];
        // fp16 store reads tile[2j][ei] (R3 bug was the swap).
        int e0 = bid * 64;
        int li = threadIdx.x & 63;
        int lo = threadIdx.x >> 6;
        #pragma unroll
        for (int k = 0; k < 16; ++k) {
            int b = lo + 4 * k;
            int e = e0 + li;
            tile[b][li] = (e < N_E) ? x[(size_t)b * N_E + e] : 0.0f;
        }
        __syncthreads();
        #pragma unroll
        for (int k = 0; k < 8; ++k) {
            int idx = k * 256 + threadIdx.x;     // 0..2047
            int ei  = idx >> 5;                  // entity 0..63
            int j   = idx & 31;                  // half2 col (batch pair) 0..31
            int e   = e0 + ei;
            if (e < N_E)
                xT[(size_t)e * 32 + j] = __floats2half2_rn(tile[2 * j][ei], tile[2 * j + 1][ei]);
        }
    } else if (bid < tgrid + rblocks) {
        // rT layout: [layer][N_R][64] (batch innermost, matches lane)
        int rb = bid - tgrid;
        int bx = rb % nrx;
        int by = rb / nrx;
        int lane = threadIdx.x & 63;
        int wv   = threadIdx.x >> 6;
        int b    = by * 4 + wv;
        int it   = bx * 64 + lane;
        if (it >= 3 * N_R) return;
        int l = it / N_R;
        int j = it - l * N_R;
        const float* W  = (l == 0) ? W1 : (l == 1) ? W2 : W3;
        const float* bv = (l == 0) ? b1 : (l == 1) ? b2 : b3;
        const float* qrow = q + (size_t)b * N_W2V;
        float a0 = 0.f, a1 = 0.f, a2 = 0.f, a3 = 0.f;
        int k = 0;
        for (; k + 4 <= N_W2V; k += 4) {
            a0 = fmaf(qrow[k + 0], W[(size_t)(k + 0) * N_R + j], a0);
            a1 = fmaf(qrow[k + 1], W[(size_t)(k + 1) * N_R + j], a1);
            a2 = fmaf(qrow[k + 2], W[(size_t)(k + 2) * N_R + j], a2);
            a3 = fmaf(qrow[k + 3], W[(size_t)(k + 3) * N_R + j], a3);
        }
        for (; k < N_W2V; ++k)
            a0 = fmaf(qrow[k], W[(size_t)k * N_R + j], a0);
        rT[(size_t)it * WAVE + b] = bv[j] + ((a0 + a1) + (a2 + a3));
    } else {
        // zero cnt + novf: (N_E+4) ints = zcount int4's exactly (N_E=200000)
        int zb = bid - tgrid - rblocks;
        int i4 = zb * 256 + threadIdx.x;
        if (i4 < zcount) ((v4i*)cnt)[i4] = (v4i){0, 0, 0, 0};
    }
}

// ---- bucket build ----
// R5: XCD group only touches its own entity slice (write coherence).
// R14: one fixed-capacity atomic pass; overflow list merged post-hop.
// R15 (nt loads): WRITE 65->52MB but FETCH 49->72MB (broke L3 stream
// sharing) -> net loss. R16 (2-pass partition): cross-XCD cursor ping-pong
// (127us) + pass2 still ~42us -> 1M random atomics cost 42-54us in THREE
// different structures => atomic floor, not cache layout. R17: revert to
// R14 + explicit atomic ILP (compute 4 (oo,pk), issue 4 independent
// atomicAdds, then 4 dependent stores; VGPR=12 said compiler serialized).

__global__ void scatter_direct_kernel(const int* __restrict__ subj, const int* __restrict__ rel,
                                      const int* __restrict__ obj,
                                      int* __restrict__ cnt, unsigned* __restrict__ slots,
                                      int* __restrict__ novf, int* __restrict__ ovf_obj,
                                      unsigned* __restrict__ ovf_pk, int nT, int nE) {
    int grp = blockIdx.x & (NXCD - 1);
    int sh  = (nE + NXCD - 1) / NXCD;
    int lo  = grp * sh;
    int hi  = min(nE, lo + sh);
    int tid    = (blockIdx.x >> 3) * blockDim.x + threadIdx.x;
    int stride = (gridDim.x >> 3) * blockDim.x;
    int nT4 = nT >> 2;
    const v4i* obj4 = (const v4i*)obj;
    for (int t = tid; t < nT4; t += stride) {
        v4i o = obj4[t];
        int base = t * 4;
        int  oo[4];
        bool mk[4];
        unsigned pk[4];
        int  slot[4];
        #pragma unroll
        for (int u = 0; u < 4; ++u) {
            oo[u] = o[u];
            mk[u] = (oo[u] >= lo && oo[u] < hi);
            pk[u] = mk[u] ? ((unsigned)subj[base + u] | ((unsigned)rel[base + u] << 18)) : 0u;
        }
        #pragma unroll
        for (int u = 0; u < 4; ++u)          // phase 1: independent atomics in flight
            if (mk[u]) slot[u] = atomicAdd(&cnt[oo[u]], 1);
        #pragma unroll
        for (int u = 0; u < 4; ++u) {        // phase 2: dependent stores
            if (mk[u]) {
                if (slot[u] < CAP) slots[(size_t)oo[u] * CAP + slot[u]] = pk[u];
                else {
                    int oi = atomicAdd(novf, 1);
                    if (oi < OVF_CAP) { ovf_obj[oi] = oo[u]; ovf_pk[oi] = pk[u]; }
                }
            }
        }
    }
    for (int t = nT4 * 4 + tid; t < nT; t += stride) {
        int oo = obj[t];
        if (oo >= lo && oo < hi) {
            unsigned pk = (unsigned)subj[t] | ((unsigned)rel[t] << 18);
            int slot = atomicAdd(&cnt[oo], 1);
            if (slot < CAP) slots[(size_t)oo * CAP + slot] = pk;
            else {
                int oi = atomicAdd(novf, 1);
                if (oi < OVF_CAP) { ovf_obj[oi] = oo; ovf_pk[oi] = pk; }
            }
        }
    }
}

// ---- hops ----
// R10: fp16 intermediates. R12: fp16 x0 + unroll-8 issue-early gathers.
// R13: gather FETCH matches the distinct-line floor; combined traffic
// 166MB/48us = 3.46TB/s ~ random-line BW -> hops at structural floor.
// R14: bucket = slots[e*CAP ..), one 64B line; no tail loop.

__device__ __forceinline__ float4 h4_to_f4(uint2 v) {
    float2 f0 = __half22float2(*(__half2*)&v.x);
    float2 f1 = __half22float2(*(__half2*)&v.y);
    return make_float4(f0.x, f0.y, f1.x, f1.y);
}

__device__ __forceinline__ uint2 pack_half4(float4 a) {
    __half2 h0 = __floats2half2_rn(a.x, a.y);
    __half2 h1 = __floats2half2_rn(a.z, a.w);
    uint2 v;
    v.x = *(unsigned*)&h0;
    v.y = *(unsigned*)&h1;
    return v;
}

// 4 entities/wave, 16 lanes x uint2 (8B) per fp16 entity row.
__device__ __forceinline__ float4 hop_accum4(const uint2* __restrict__ xp,
                                             const float4* __restrict__ r_lds,
                                             const int* __restrict__ cnt,
                                             const unsigned* __restrict__ slots,
                                             int e, int g, int c, int nE) {
    float4 acc = make_float4(0.f, 0.f, 0.f, 0.f);
    int len = (e < nE) ? min(cnt[e], CAP) : 0;
    unsigned pv = (c < len) ? slots[(size_t)e * CAP + c] : 0u;  // whole bucket = one 64B line
    int m = max(len, __shfl_xor(len, 16));            // wave-max over the 4 groups
    m = max(m, __shfl_xor(m, 32));
    for (int j0 = 0; j0 < m; j0 += 8) {
        uint2 xv[8];
        unsigned pr[8];
        #pragma unroll
        for (int u = 0; u < 8; ++u) {                 // issue all 8 gathers first
            int jj = max(min(j0 + u, len - 1), 0);    // clamp: dup loads hit hot lines
            unsigned p = __shfl(pv, (g << 4) + jj);   // per-lane src index: group-local broadcast
            pr[u] = p >> 18;
            xv[u] = xp[(size_t)(p & 0x3FFFFu) * 16 + c];
        }
        #pragma unroll
        for (int u = 0; u < 8; ++u) {                 // consume with LDS-r FMAs
            if (j0 + u < len) {
                float4 rv = r_lds[pr[u] * RSTRIDE + c];
                float4 xf = h4_to_f4(xv[u]);
                acc.x = fmaf(xf.x, rv.x, acc.x);
                acc.y = fmaf(xf.y, rv.y, acc.y);
                acc.z = fmaf(xf.z, rv.z, acc.z);
                acc.w = fmaf(xf.w, rv.w, acc.w);
            }
        }
    }
    return acc;
}

// hops 1-2: 1024-thread blocks (16 waves x 4 entities = 64-entity tiles),
// grid-stride, 512 resident blocks (2/CU, 32 waves/CU). fp16 in, fp16 out.
__global__ __launch_bounds__(HOP_TPB, 8)
void hop_mid_kernel(const uint2* __restrict__ xp, const float4* __restrict__ rT4,
                    const int* __restrict__ cnt, const unsigned* __restrict__ slots,
                    uint2* __restrict__ yh, int nE, int nR) {
    __shared__ float4 r_lds[NRMAX * RSTRIDE];
    for (int i = threadIdx.x; i < nR * 16; i += HOP_TPB)
        r_lds[(i >> 4) * RSTRIDE + (i & 15)] = rT4[i];
    __syncthreads();
    int lane = threadIdx.x & 63;
    int g = lane >> 4, c = lane & 15;
    int wv = threadIdx.x >> 6;                   // 0..15
    int nTiles = (nE + 63) >> 6;
    for (int t = blockIdx.x; t < nTiles; t += gridDim.x) {
        int e = t * 64 + wv * 4 + g;
        float4 acc = hop_accum4(xp, r_lds, cnt, slots, e, g, c, nE);
        if (e < nE) yh[(size_t)e * 16 + c] = pack_half4(acc);
    }
}

// hop 3 fused with output transpose: 64-entity LDS tile, stores (B, N_E) fp32.
__global__ __launch_bounds__(HOP_TPB, 8)
void hop_out_kernel(const uint2* __restrict__ xp, const float4* __restrict__ rT4,
                    const int* __restrict__ cnt, const unsigned* __restrict__ slots,
                    float* __restrict__ out, int nE, int nR) {
    __shared__ float4 r_lds[NRMAX * RSTRIDE];
    __shared__ float tile[64][65];
    for (int i = threadIdx.x; i < nR * 16; i += HOP_TPB)
        r_lds[(i >> 4) * RSTRIDE + (i & 15)] = rT4[i];
    __syncthreads();
    int lane = threadIdx.x & 63;
    int g = lane >> 4, c = lane & 15;
    int wv = threadIdx.x >> 6;                   // 0..15
    int nTiles = (nE + 63) >> 6;
    for (int t = blockIdx.x; t < nTiles; t += gridDim.x) {
        int e0 = t * 64;
        int ei = wv * 4 + g;                     // 0..63 unique per (wv,g)
        float4 acc = hop_accum4(xp, r_lds, cnt, slots, e0 + ei, g, c, nE);
        tile[ei][4 * c + 0] = acc.x;
        tile[ei][4 * c + 1] = acc.y;
        tile[ei][4 * c + 2] = acc.z;
        tile[ei][4 * c + 3] = acc.w;
        __syncthreads();
        #pragma unroll
        for (int k = 0; k < 4; ++k) {
            int b = wv * 4 + k;
            int e = e0 + lane;
            if (e < nE) out[(size_t)b * nE + e] = tile[lane][b];
        }
        __syncthreads();                         // tile reused next iteration
    }
}

// ---- overflow merge (exercised every run on ~3 triples) ----
__device__ __forceinline__ void atom_add_h2(unsigned* addr, float a, float b) {
    unsigned old = __atomic_load_n(addr, __ATOMIC_RELAXED), assumed;
    do {
        assumed = old;
        float2 f = __half22float2(*(__half2*)&assumed);
        __half2 nh = __floats2half2_rn(f.x + a, f.y + b);
        old = atomicCAS(addr, assumed, *(unsigned*)&nh);
    } while (old != assumed);
}

// adds overflow contributions into fp16 (N_E,64) intermediate
__global__ void ovf_mid_kernel(const uint2* __restrict__ xp, const float* __restrict__ rTl,
                               const int* __restrict__ novf, const int* __restrict__ ovf_obj,
                               const unsigned* __restrict__ ovf_pk, uint2* __restrict__ yh) {
    int n = min(*novf, OVF_CAP);
    int c = threadIdx.x & 15, grp = threadIdx.x >> 4;   // 64 threads = 4 groups
    for (int i = blockIdx.x * 4 + grp; i < n; i += gridDim.x * 4) {
        int o = ovf_obj[i];
        unsigned p = ovf_pk[i];
        float4 xf = h4_to_f4(xp[(size_t)(p & 0x3FFFFu) * 16 + c]);
        const float* rr = rTl + (size_t)(p >> 18) * 64 + c * 4;
        unsigned* w = (unsigned*)&yh[(size_t)o * 16 + c];
        atom_add_h2(w,     xf.x * rr[0], xf.y * rr[1]);
        atom_add_h2(w + 1, xf.z * rr[2], xf.w * rr[3]);
    }
}

// adds overflow contributions into fp32 (B, N_E) output
__global__ void ovf_out_kernel(const uint2* __restrict__ xp, const float* __restrict__ rTl,
                               const int* __restrict__ novf, const int* __restrict__ ovf_obj,
                               const unsigned* __restrict__ ovf_pk, float* __restrict__ out, int nE) {
    int n = min(*novf, OVF_CAP);
    int c = threadIdx.x & 15, grp = threadIdx.x >> 4;
    for (int i = blockIdx.x * 4 + grp; i < n; i += gridDim.x * 4) {
        int o = ovf_obj[i];
        unsigned p = ovf_pk[i];
        float4 xf = h4_to_f4(xp[(size_t)(p & 0x3FFFFu) * 16 + c]);
        const float* rr = rTl + (size_t)(p >> 18) * 64 + c * 4;
        atomicAdd(&out[(size_t)(4 * c + 0) * nE + o], xf.x * rr[0]);
        atomicAdd(&out[(size_t)(4 * c + 1) * nE + o], xf.y * rr[1]);
        atomicAdd(&out[(size_t)(4 * c + 2) * nE + o], xf.z * rr[2]);
        atomicAdd(&out[(size_t)(4 * c + 3) * nE + o], xf.w * rr[3]);
    }
}

extern "C" void kernel_launch(void* const* d_in, const int* in_sizes, int n_in,
                              void* d_out, int out_size, void* d_ws, size_t ws_size,
                              hipStream_t stream) {
    const float* x  = (const float*)d_in[0];
    const float* q  = (const float*)d_in[1];
    const float* W1 = (const float*)d_in[2];
    const float* b1 = (const float*)d_in[3];
    const float* W2 = (const float*)d_in[4];
    const float* b2 = (const float*)d_in[5];
    const float* W3 = (const float*)d_in[6];
    const float* b3 = (const float*)d_in[7];
    const int* subj = (const int*)d_in[8];
    const int* rel  = (const int*)d_in[9];
    const int* obj  = (const int*)d_in[10];
    // n_hop (d_in[11]) is the constant 3 per the reference; hops hardcoded.

    const int B     = 64;
    const int N_E   = in_sizes[0] / B;   // 200000
    const int N_W2V = in_sizes[1] / B;   // 300
    const int N_R   = in_sizes[3];       // 200
    const int N_T   = in_sizes[8];       // 1000000

    const size_t h16bytes = (size_t)N_E * B * sizeof(__half);   // 25.6MB per fp16 buffer

    // ws layout: [cnt nE][novf 4][ovf_obj][ovf_pk][slots nE*CAP][rT][X0 fp16][H1 fp16?]
    int*      cnt     = (int*)d_ws;
    int*      novf    = cnt + N_E;
    int*      ovf_obj = novf + 4;
    unsigned* ovf_pk  = (unsigned*)(ovf_obj + OVF_CAP);
    unsigned* slots   = ovf_pk + OVF_CAP;
    char*     rT_raw  = (char*)(slots + (size_t)N_E * CAP);
    float*    rT      = (float*)(((uintptr_t)rT_raw + 15) & ~(uintptr_t)15);
    char*     X0      = (char*)(rT + (size_t)3 * N_R * B);      // 16B-aligned
    size_t used = (size_t)(X0 - (char*)d_ws) + h16bytes;

    char* H1;
    if (ws_size >= used + h16bytes) {
        H1 = X0 + h16bytes;
        used += h16bytes;
    } else {
        H1 = (char*)d_out;   // 25.6MB scratch in the 51.2MB output; dead before hop3's write
    }
    char* H2 = X0;           // X0 dead after hop1

    // 1) fused prologue: transpose + compute_r + cnt/novf zeroing
    int tgrid   = (N_E + 63) / 64;               // 3125
    int nrx     = (3 * N_R + 63) / 64;           // 10
    int rblocks = nrx * (B / 4);                 // 160
    int zcount  = (N_E + 4) / 4;                 // 50001 int4 (N_E+4 divisible by 4)
    int zblocks = (zcount + 255) / 256;          // 196
    prologue_kernel<<<tgrid + rblocks + zblocks, 256, 0, stream>>>(
        x, q, W1, b1, W2, b2, W3, b3, rT, (__half2*)X0, cnt,
        N_E, N_R, N_W2V, tgrid, nrx, rblocks, zcount);

    // 2) bucket build: one XCD-sharded atomic pass
    scatter_direct_kernel<<<CSR_BLOCKS, CSR_TPB, 0, stream>>>(
        subj, rel, obj, cnt, slots, novf, ovf_obj, ovf_pk, N_T, N_E);

    // 3) three hops (+ tiny overflow merge after each); hop3 fuses the transpose
    int hblocks = tgrid < HOP_BLOCKS ? tgrid : HOP_BLOCKS;
    const float* rT1 = rT;
    const float* rT2 = rT + (size_t)1 * N_R * B;
    const float* rT3 = rT + (size_t)2 * N_R * B;

    hop_mid_kernel<<<hblocks, HOP_TPB, 0, stream>>>(
        (const uint2*)X0, (const float4*)rT1, cnt, slots, (uint2*)H1, N_E, N_R);
    ovf_mid_kernel<<<16, 64, 0, stream>>>(
        (const uint2*)X0, rT1, novf, ovf_obj, ovf_pk, (uint2*)H1);

    hop_mid_kernel<<<hblocks, HOP_TPB, 0, stream>>>(
        (const uint2*)H1, (const float4*)rT2, cnt, slots, (uint2*)H2, N_E, N_R);
    ovf_mid_kernel<<<16, 64, 0, stream>>>(
        (const uint2*)H1, rT2, novf, ovf_obj, ovf_pk, (uint2*)H2);

    hop_out_kernel<<<hblocks, HOP_TPB, 0, stream>>>(
        (const uint2*)H2, (const float4*)rT3, cnt, slots, (float*)d_out, N_E, N_R);
    ovf_out_kernel<<<16, 64, 0, stream>>>(
        (const uint2*)H2, rT3, novf, ovf_obj, ovf_pk, (float*)d_out, N_E);
}